// Round 2
// baseline (1218.484 us; speedup 1.0000x reference)
//
#include <hip/hip_runtime.h>

typedef __attribute__((ext_vector_type(8))) unsigned short u16x8;
typedef __attribute__((ext_vector_type(4))) unsigned short u16x4;
typedef __attribute__((ext_vector_type(8))) __bf16 bf16x8;
typedef __attribute__((ext_vector_type(4))) float f32x4;

#define DEVINL __device__ __forceinline__

DEVINL f32x4 MF(u16x8 a, u16x8 b, f32x4 c) {
  return __builtin_amdgcn_mfma_f32_16x16x32_bf16(
      __builtin_bit_cast(bf16x8, a), __builtin_bit_cast(bf16x8, b), c, 0, 0, 0);
}
DEVINL unsigned short f2b(float f) {          // f32 -> bf16 RNE
  unsigned u = __builtin_bit_cast(unsigned, f);
  u += 0x7FFFu + ((u >> 16) & 1u);
  return (unsigned short)(u >> 16);
}
DEVINL float b2f(unsigned short h) {
  unsigned u = ((unsigned)h) << 16;
  return __builtin_bit_cast(float, u);
}

// ---------------------------------------------------------------- k_prep
// Build K-contiguous bf16 weight copies:
//  Wt_in [128c][256h], Wc [2][9kk][128o][128i], Wt_out [256h][128c]
__global__ void k_prep(const float* __restrict__ W_in, const float* __restrict__ conv_w,
                       const float* __restrict__ W_out, unsigned short* __restrict__ Wt_in,
                       unsigned short* __restrict__ Wc, unsigned short* __restrict__ Wt_out) {
  int t = blockIdx.x * 256 + threadIdx.x;
  if (t < 128 * 256) { int c = t >> 8, h = t & 255; Wt_in[t] = f2b(W_in[h * 128 + c]); }
  if (t < 256 * 128) { int h = t >> 7, c = t & 127; Wt_out[t] = f2b(W_out[c * 256 + h]); }
  for (int i = t; i < 2 * 9 * 128 * 128; i += 65536) {
    int ii = i & 127, o = (i >> 7) & 127, rest = i >> 14;
    int kk = rest % 9, L = rest / 9;
    Wc[i] = f2b(conv_w[(size_t)((L * 128 + o) * 128 + ii) * 9 + kk]);
  }
}

// ---------------------------------------------------------------- k_proj_in
// grid0[b][c][s] = sum_h W_in[h][c]*x[b][s][h] + b_in[c]; cells 120..143 = 0
__global__ __launch_bounds__(256) void k_proj_in(
    const float* __restrict__ x, const unsigned short* __restrict__ Wt_in,
    const float* __restrict__ b_in, unsigned short* __restrict__ gridb) {
  __shared__ unsigned short Xb[128 * 256];   // [s][h] bf16, 512B rows, XOR-swizzled
  char* XB = (char*)Xb;
  const int b = blockIdx.x;
  const float* xb = x + (size_t)b * 120 * 256;

  for (int idx = threadIdx.x; idx < (120 * 256) / 4; idx += 256) {
    int row = idx >> 6, col = (idx & 63) << 2;
    f32x4 v = *(const f32x4*)(xb + row * 256 + col);
    u16x4 h = { f2b(v[0]), f2b(v[1]), f2b(v[2]), f2b(v[3]) };
    *(u16x4*)(XB + row * 512 + ((col * 2) ^ ((row & 7) << 4))) = h;
  }
  for (int idx = threadIdx.x; idx < (8 * 256) / 4; idx += 256) {  // zero-pad rows 120..127
    int row = 120 + (idx >> 6), col = (idx & 63) << 2;
    u16x4 zz = {0, 0, 0, 0};
    *(u16x4*)(XB + row * 512 + ((col * 2) ^ ((row & 7) << 4))) = zz;
  }
  __syncthreads();

  const int l = threadIdx.x & 63, hi = l >> 4, lo = l & 15, w = threadIdx.x >> 6;
  const f32x4 Z = {0.f, 0.f, 0.f, 0.f};
  f32x4 acc[2][8];
#pragma unroll
  for (int a = 0; a < 2; ++a)
#pragma unroll
    for (int n = 0; n < 8; ++n) acc[a][n] = Z;

  const unsigned short* A0 = Wt_in + (w * 32 + lo) * 256;
  const unsigned short* A1 = A0 + 16 * 256;
#pragma unroll
  for (int ks = 0; ks < 8; ++ks) {
    const int kb = ks * 32 + hi * 8;
    u16x8 a0 = *(const u16x8*)(A0 + kb);
    u16x8 a1 = *(const u16x8*)(A1 + kb);
#pragma unroll
    for (int nt = 0; nt < 8; ++nt) {
      int row = nt * 16 + lo;
      u16x8 bf = *(const u16x8*)(XB + row * 512 + ((kb * 2) ^ ((row & 7) << 4)));
      acc[0][nt] = MF(a0, bf, acc[0][nt]);
      acc[1][nt] = MF(a1, bf, acc[1][nt]);
    }
  }

  unsigned short* gb = gridb + (size_t)b * 128 * 144;
#pragma unroll
  for (int am = 0; am < 2; ++am)
#pragma unroll
    for (int r = 0; r < 4; ++r) {
      const int crow = w * 32 + am * 16 + hi * 4 + r;
      const float bias = b_in[crow];
#pragma unroll
      for (int nt = 0; nt < 8; ++nt) {
        int s = nt * 16 + lo;
        if (s < 120) gb[crow * 144 + s] = f2b(acc[am][nt][r] + bias);
      }
    }
  for (int idx = threadIdx.x; idx < 128 * 24; idx += 256) {  // zero cells 120..143
    int c = idx / 24, p = idx - c * 24;
    gb[c * 144 + 120 + p] = 0;
  }
}

// ---------------------------------------------------------------- k_conv
// stage = grid (optionally + relu(bn_prev(y_prev))), 3x3 dilated conv over 12x12,
// write y, per-block BN partial sums. Optionally write staged grid back.
__global__ __launch_bounds__(256) void k_conv(
    unsigned short* __restrict__ gridb, unsigned short* __restrict__ ybuf,
    const float* __restrict__ statsP, const unsigned short* __restrict__ WcL,
    const float* __restrict__ convbL, float* __restrict__ partials,
    int dil, int writeback) {
  __shared__ unsigned short Gt[145 * 128];   // [p][i] bf16, 256B rows, swizzled; row 144 = zeros
  char* GT = (char*)Gt;
  const int b = blockIdx.x;
  unsigned short* gbp = gridb + (size_t)b * 128 * 144;
  unsigned short* ybp = ybuf + (size_t)b * 128 * 144;

  for (int idx = threadIdx.x; idx < 128 * 18; idx += 256) {
    int c = idx / 18;
    int p0 = (idx - c * 18) * 8;
    u16x8 g = *(const u16x8*)(gbp + c * 144 + p0);
    if (statsP) {
      u16x8 yv = *(const u16x8*)(ybp + c * 144 + p0);
      float a = statsP[c], bb = statsP[128 + c];
#pragma unroll
      for (int j = 0; j < 8; ++j)
        g[j] = f2b(b2f(g[j]) + fmaxf(0.f, b2f(yv[j]) * a + bb));
      if (writeback) *(u16x8*)(gbp + c * 144 + p0) = g;
    }
#pragma unroll
    for (int j = 0; j < 8; ++j) {
      int p = p0 + j;
      *(unsigned short*)(GT + p * 256 + ((c * 2) ^ ((p & 7) << 4))) = g[j];
    }
  }
  if (threadIdx.x < 64) *(unsigned*)(GT + 144 * 256 + threadIdx.x * 4) = 0u;
  __syncthreads();

  const int l = threadIdx.x & 63, hi = l >> 4, lo = l & 15, w = threadIdx.x >> 6;
  const f32x4 Z = {0.f, 0.f, 0.f, 0.f};
  f32x4 acc[2][9];
#pragma unroll
  for (int a = 0; a < 2; ++a)
#pragma unroll
    for (int n = 0; n < 9; ++n) acc[a][n] = Z;

  int pr[9], pc[9];
#pragma unroll
  for (int nt = 0; nt < 9; ++nt) {
    int p = nt * 16 + lo;
    pr[nt] = p / 12;
    pc[nt] = p - pr[nt] * 12;
  }

  for (int off = 0; off < 9; ++off) {
    const int dh = (off / 3 - 1) * dil, dw = (off % 3 - 1) * dil;
    int rb[9], sz[9];
#pragma unroll
    for (int nt = 0; nt < 9; ++nt) {
      int r2 = pr[nt] + dh, c2 = pc[nt] + dw;
      bool ok = ((unsigned)r2 < 12u) && ((unsigned)c2 < 12u);
      int ps = ok ? (r2 * 12 + c2) : 144;     // 144 = zero row (padding)
      rb[nt] = ps * 256;
      sz[nt] = (ps & 7) << 4;
    }
    const unsigned short* Ao = WcL + off * (128 * 128);
#pragma unroll
    for (int ks = 0; ks < 4; ++ks) {
      const int kb = ks * 32 + hi * 8;
      u16x8 a0 = *(const u16x8*)(Ao + (w * 32 + lo) * 128 + kb);
      u16x8 a1 = *(const u16x8*)(Ao + (w * 32 + 16 + lo) * 128 + kb);
#pragma unroll
      for (int nt = 0; nt < 9; ++nt) {
        u16x8 bf = *(const u16x8*)(GT + rb[nt] + ((kb * 2) ^ sz[nt]));
        acc[0][nt] = MF(a0, bf, acc[0][nt]);
        acc[1][nt] = MF(a1, bf, acc[1][nt]);
      }
    }
  }

#pragma unroll
  for (int am = 0; am < 2; ++am)
#pragma unroll
    for (int r = 0; r < 4; ++r) {
      const int orow = w * 32 + am * 16 + hi * 4 + r;
      const float bias = convbL[orow];
      float s1 = 0.f, s2 = 0.f;
#pragma unroll
      for (int nt = 0; nt < 9; ++nt) {
        float yv = acc[am][nt][r] + bias;
        s1 += yv; s2 += yv * yv;
        ybp[orow * 144 + nt * 16 + lo] = f2b(yv);
      }
#pragma unroll
      for (int m = 1; m < 16; m <<= 1) { s1 += __shfl_xor(s1, m); s2 += __shfl_xor(s2, m); }
      if (lo == 0) {
        partials[(size_t)orow * 4096 + b] = s1;
        partials[(size_t)(128 + orow) * 4096 + b] = s2;
      }
    }
}

// ---------------------------------------------------------------- k_stats
__global__ void k_stats(const float* __restrict__ partials, const float* __restrict__ bn_g,
                        const float* __restrict__ bn_b, float* __restrict__ statsL, float invN) {
  const int c = blockIdx.x, t = threadIdx.x;
  float s1 = 0.f, s2 = 0.f;
  const float* p1 = partials + (size_t)c * 4096;
  const float* p2 = partials + (size_t)(128 + c) * 4096;
  for (int j = t; j < 4096; j += 256) { s1 += p1[j]; s2 += p2[j]; }
#pragma unroll
  for (int m = 1; m < 64; m <<= 1) { s1 += __shfl_xor(s1, m); s2 += __shfl_xor(s2, m); }
  __shared__ float r1[4], r2[4];
  if ((t & 63) == 0) { r1[t >> 6] = s1; r2[t >> 6] = s2; }
  __syncthreads();
  if (t == 0) {
    float S1 = r1[0] + r1[1] + r1[2] + r1[3];
    float S2 = r2[0] + r2[1] + r2[2] + r2[3];
    float mean = S1 * invN;
    float var = fmaxf(S2 * invN - mean * mean, 0.f);
    float a = bn_g[c] * rsqrtf(var + 1e-5f);
    statsL[c] = a;
    statsL[128 + c] = bn_b[c] - mean * a;
  }
}

// ---------------------------------------------------------------- k_out
// stage Gt[s][c] = grid1 + relu(bn2(y2)); h2 = Gt @ W_out; z = x + h2 + b_out; LayerNorm.
__global__ __launch_bounds__(256) void k_out(
    const unsigned short* __restrict__ gridb, const unsigned short* __restrict__ ybuf,
    const float* __restrict__ statsP, const unsigned short* __restrict__ Wt_out,
    const float* __restrict__ b_out, const float* __restrict__ x,
    const float* __restrict__ ln_g, const float* __restrict__ ln_b,
    float* __restrict__ out) {
  __shared__ unsigned short Gs[128 * 128];   // [s][c] bf16, 256B rows, swizzled
  char* GT = (char*)Gs;
  const int b = blockIdx.x;
  const unsigned short* gbp = gridb + (size_t)b * 128 * 144;
  const unsigned short* ybp = ybuf + (size_t)b * 128 * 144;

  for (int idx = threadIdx.x; idx < 128 * 15; idx += 256) {   // only s<120 needed
    int c = idx / 15;
    int p0 = (idx - c * 15) * 8;
    u16x8 g = *(const u16x8*)(gbp + c * 144 + p0);
    u16x8 yv = *(const u16x8*)(ybp + c * 144 + p0);
    float a = statsP[c], bb = statsP[128 + c];
#pragma unroll
    for (int j = 0; j < 8; ++j) {
      float v = b2f(g[j]) + fmaxf(0.f, b2f(yv[j]) * a + bb);
      int s = p0 + j;
      *(unsigned short*)(GT + s * 256 + ((c * 2) ^ ((s & 7) << 4))) = f2b(v);
    }
  }
  for (int idx = threadIdx.x; idx < 512; idx += 256)          // zero rows 120..127
    *(unsigned*)(GT + 120 * 256 + idx * 4) = 0u;
  __syncthreads();

  const int l = threadIdx.x & 63, hi = l >> 4, lo = l & 15, w = threadIdx.x >> 6;
  const f32x4 Z = {0.f, 0.f, 0.f, 0.f};
  f32x4 acc[2][16];
#pragma unroll
  for (int a = 0; a < 2; ++a)
#pragma unroll
    for (int n = 0; n < 16; ++n) acc[a][n] = Z;

#pragma unroll
  for (int ks = 0; ks < 4; ++ks) {
    const int kb = ks * 32 + hi * 8;
    const int r0 = w * 32 + lo, r1 = r0 + 16;
    u16x8 a0 = *(const u16x8*)(GT + r0 * 256 + ((kb * 2) ^ ((r0 & 7) << 4)));
    u16x8 a1 = *(const u16x8*)(GT + r1 * 256 + ((kb * 2) ^ ((r1 & 7) << 4)));
#pragma unroll
    for (int nt = 0; nt < 16; ++nt) {
      u16x8 bf = *(const u16x8*)(Wt_out + (nt * 16 + lo) * 128 + kb);
      acc[0][nt] = MF(a0, bf, acc[0][nt]);
      acc[1][nt] = MF(a1, bf, acc[1][nt]);
    }
  }

  const float* xb = x + (size_t)b * 120 * 256;
  float* ob = out + (size_t)b * 120 * 256;
#pragma unroll
  for (int am = 0; am < 2; ++am)
#pragma unroll
    for (int r = 0; r < 4; ++r) {
      const int row = w * 32 + am * 16 + hi * 4 + r;
      if (row < 120) {    // uniform within each 16-lane group -> shfl below is safe
        float z[16];
        float s1 = 0.f, s2 = 0.f;
#pragma unroll
        for (int nt = 0; nt < 16; ++nt) {
          const int col = nt * 16 + lo;
          float v = acc[am][nt][r] + b_out[col] + xb[row * 256 + col];
          z[nt] = v; s1 += v; s2 += v * v;
        }
#pragma unroll
        for (int m = 1; m < 16; m <<= 1) { s1 += __shfl_xor(s1, m); s2 += __shfl_xor(s2, m); }
        const float mu = s1 * (1.f / 256.f);
        const float var = fmaxf(s2 * (1.f / 256.f) - mu * mu, 0.f);
        const float rs = rsqrtf(var + 1e-5f);
#pragma unroll
        for (int nt = 0; nt < 16; ++nt) {
          const int col = nt * 16 + lo;
          ob[row * 256 + col] = (z[nt] - mu) * rs * ln_g[col] + ln_b[col];
        }
      }
    }
}

// ---------------------------------------------------------------- launch
extern "C" void kernel_launch(void* const* d_in, const int* in_sizes, int n_in,
                              void* d_out, int out_size, void* d_ws, size_t ws_size,
                              hipStream_t stream) {
  (void)in_sizes; (void)n_in; (void)out_size; (void)ws_size;
  const float* x      = (const float*)d_in[0];
  const float* W_in   = (const float*)d_in[1];
  const float* b_in   = (const float*)d_in[2];
  const float* conv_w = (const float*)d_in[3];
  const float* conv_b = (const float*)d_in[4];
  const float* bn_g   = (const float*)d_in[5];
  const float* bn_b   = (const float*)d_in[6];
  const float* W_out  = (const float*)d_in[7];
  const float* b_out  = (const float*)d_in[8];
  const float* ln_g   = (const float*)d_in[9];
  const float* ln_b   = (const float*)d_in[10];

  char* ws = (char*)d_ws;
  size_t off = 0;
  auto alloc = [&](size_t bytes) { char* p = ws + off; off = (off + bytes + 255) & ~(size_t)255; return p; };
  unsigned short* Wt_in  = (unsigned short*)alloc(128 * 256 * 2);
  unsigned short* Wc     = (unsigned short*)alloc(2 * 9 * 128 * 128 * 2);
  unsigned short* Wt_out = (unsigned short*)alloc(256 * 128 * 2);
  float* stats           = (float*)alloc(2 * 256 * 4);
  float* partials        = (float*)alloc((size_t)256 * 4096 * 4);
  unsigned short* gridb  = (unsigned short*)alloc((size_t)4096 * 128 * 144 * 2);
  unsigned short* ybuf   = (unsigned short*)alloc((size_t)4096 * 128 * 144 * 2);

  const float invN = 1.f / (4096.f * 144.f);

  k_prep<<<256, 256, 0, stream>>>(W_in, conv_w, W_out, Wt_in, Wc, Wt_out);
  k_proj_in<<<4096, 256, 0, stream>>>(x, Wt_in, b_in, gridb);
  k_conv<<<4096, 256, 0, stream>>>(gridb, ybuf, nullptr, Wc, conv_b, partials, 1, 0);
  k_stats<<<128, 256, 0, stream>>>(partials, bn_g, bn_b, stats, invN);
  k_conv<<<4096, 256, 0, stream>>>(gridb, ybuf, stats, Wc + 9 * 128 * 128, conv_b + 128, partials, 2, 1);
  k_stats<<<128, 256, 0, stream>>>(partials, bn_g + 128, bn_b + 128, stats + 256, invN);
  k_out<<<4096, 256, 0, stream>>>(gridb, ybuf, stats + 256, Wt_out, b_out, x, ln_g, ln_b, (float*)d_out);
}

// Round 4
// 1133.718 us; speedup vs baseline: 1.0748x; 1.0748x over previous
//
#include <hip/hip_runtime.h>

typedef __attribute__((ext_vector_type(8))) unsigned short u16x8;
typedef __attribute__((ext_vector_type(8))) __bf16 bf16x8;
typedef __attribute__((ext_vector_type(4))) float f32x4;

#define DEVINL __device__ __forceinline__

DEVINL f32x4 MF(u16x8 a, u16x8 b, f32x4 c) {
  return __builtin_amdgcn_mfma_f32_16x16x32_bf16(
      __builtin_bit_cast(bf16x8, a), __builtin_bit_cast(bf16x8, b), c, 0, 0, 0);
}
DEVINL unsigned short f2b(float f) {          // f32 -> bf16 RNE via HW cvt
  return __builtin_bit_cast(unsigned short, (__bf16)f);
}
DEVINL float b2f(unsigned short h) {
  unsigned u = ((unsigned)h) << 16;
  return __builtin_bit_cast(float, u);
}

// ---------------------------------------------------------------- k_prep
// K-contiguous bf16 weights: Wt_in [128c][256h], Wc [2][9kk][128o][128i],
// Wt_out [256h][128c]. (All are MFMA B-operands: rows = n-index, k contiguous.)
__global__ void k_prep(const float* __restrict__ W_in, const float* __restrict__ conv_w,
                       const float* __restrict__ W_out, unsigned short* __restrict__ Wt_in,
                       unsigned short* __restrict__ Wc, unsigned short* __restrict__ Wt_out) {
  int t = blockIdx.x * 256 + threadIdx.x;
  if (t < 128 * 256) { int c = t >> 8, h = t & 255; Wt_in[t] = f2b(W_in[h * 128 + c]); }
  if (t < 256 * 128) { int h = t >> 7, c = t & 127; Wt_out[t] = f2b(W_out[c * 256 + h]); }
  for (int i = t; i < 2 * 9 * 128 * 128; i += 65536) {
    int ii = i & 127, o = (i >> 7) & 127, rest = i >> 14;
    int kk = rest % 9, L = rest / 9;
    Wc[i] = f2b(conv_w[(size_t)((L * 128 + o) * 128 + ii) * 9 + kk]);
  }
}

// ---------------------------------------------------------------- conv body
// A = grid rows [p][i] from swizzled LDS, B = Wc rows [o][i].  D[p][o].
// Writes y [p][o] + per-block BN partials.  dil inlined as constant.
DEVINL void conv_body(const char* GT, const unsigned short* __restrict__ WcL,
                      const float* __restrict__ convbL, int dil,
                      unsigned short* __restrict__ ybp, float* __restrict__ partials,
                      int b, int w, int hi, int lo) {
  const f32x4 Z = {0.f, 0.f, 0.f, 0.f};
  f32x4 acc[9][2];
#pragma unroll
  for (int mt = 0; mt < 9; ++mt) { acc[mt][0] = Z; acc[mt][1] = Z; }

  int pr[9], pc[9];
#pragma unroll
  for (int mt = 0; mt < 9; ++mt) {
    int p = mt * 16 + lo;
    pr[mt] = p / 12;
    pc[mt] = p - pr[mt] * 12;
  }

  for (int off = 0; off < 9; ++off) {
    const int dh = (off / 3 - 1) * dil, dw = (off % 3 - 1) * dil;
    int rb[9], sz[9];
#pragma unroll
    for (int mt = 0; mt < 9; ++mt) {
      int r2 = pr[mt] + dh, c2 = pc[mt] + dw;
      bool ok = ((unsigned)r2 < 12u) && ((unsigned)c2 < 12u);
      int ps = ok ? (r2 * 12 + c2) : 144;       // row 144 = zeros (padding)
      rb[mt] = ps * 256;
      sz[mt] = (ps & 7) << 4;
    }
    const unsigned short* Ao = WcL + off * (128 * 128);
#pragma unroll
    for (int ks = 0; ks < 4; ++ks) {
      const int kb = ks * 32 + hi * 8;
      u16x8 b0 = *(const u16x8*)(Ao + (w * 32 + lo) * 128 + kb);
      u16x8 b1 = *(const u16x8*)(Ao + (w * 32 + 16 + lo) * 128 + kb);
#pragma unroll
      for (int mt = 0; mt < 9; ++mt) {
        u16x8 a = *(const u16x8*)(GT + rb[mt] + ((kb * 2) ^ sz[mt]));
        acc[mt][0] = MF(a, b0, acc[mt][0]);
        acc[mt][1] = MF(a, b1, acc[mt][1]);
      }
    }
  }

  const float bias0 = convbL[w * 32 + lo], bias1 = convbL[w * 32 + 16 + lo];
  float s1a = 0.f, s2a = 0.f, s1b = 0.f, s2b = 0.f;
#pragma unroll
  for (int mt = 0; mt < 9; ++mt)
#pragma unroll
    for (int r = 0; r < 4; ++r) {
      const int p = mt * 16 + hi * 4 + r;
      float ya = acc[mt][0][r] + bias0;
      float yb = acc[mt][1][r] + bias1;
      s1a += ya; s2a += ya * ya; s1b += yb; s2b += yb * yb;
      ybp[p * 128 + w * 32 + lo]      = f2b(ya);
      ybp[p * 128 + w * 32 + 16 + lo] = f2b(yb);
    }
  s1a += __shfl_xor(s1a, 16); s1a += __shfl_xor(s1a, 32);
  s2a += __shfl_xor(s2a, 16); s2a += __shfl_xor(s2a, 32);
  s1b += __shfl_xor(s1b, 16); s1b += __shfl_xor(s1b, 32);
  s2b += __shfl_xor(s2b, 16); s2b += __shfl_xor(s2b, 32);
  if (hi == 0) {
    const int o0 = w * 32 + lo;
    partials[(size_t)o0 * 4096 + b]              = s1a;
    partials[(size_t)(128 + o0) * 4096 + b]      = s2a;
    partials[(size_t)(o0 + 16) * 4096 + b]       = s1b;
    partials[(size_t)(128 + o0 + 16) * 4096 + b] = s2b;
  }
}

// ---------------------------------------------------------------- k_in
// Fused proj_in + conv1.  grid0[b][p][c] (p-major), y1[b][p][o], partials.
// proj: A = x rows [s][h] straight from global (coalesced 128B/row), B = Wt_in.
__global__ __launch_bounds__(256) void k_in(
    const float* __restrict__ x, const unsigned short* __restrict__ Wt_in,
    const float* __restrict__ b_in, const unsigned short* __restrict__ Wc0,
    const float* __restrict__ convb0, unsigned short* __restrict__ gridb,
    unsigned short* __restrict__ ybuf, float* __restrict__ partials) {
  __shared__ unsigned short Gt[145 * 128];   // [p][c] bf16, 256B rows, swizzled
  char* GT = (char*)Gt;
  const int b = blockIdx.x, t = threadIdx.x;
  const int l = t & 63, hi = l >> 4, lo = l & 15, w = t >> 6;
  const float* xb = x + (size_t)b * 120 * 256;

  const f32x4 Z = {0.f, 0.f, 0.f, 0.f};
  f32x4 acc[2][8];
#pragma unroll
  for (int mi = 0; mi < 2; ++mi)
#pragma unroll
    for (int cn = 0; cn < 8; ++cn) acc[mi][cn] = Z;

#pragma unroll
  for (int ks = 0; ks < 8; ++ks) {
    const int kb = ks * 32 + hi * 8;
    u16x8 af[2];
#pragma unroll
    for (int mi = 0; mi < 2; ++mi) {
      int s = w * 32 + mi * 16 + lo;
      s = s < 120 ? s : 119;                  // clamp (values discarded later)
      const float* px = xb + s * 256 + kb;
      f32x4 v0 = *(const f32x4*)px;
      f32x4 v1 = *(const f32x4*)(px + 4);
      u16x8 a;
#pragma unroll
      for (int j = 0; j < 4; ++j) { a[j] = f2b(v0[j]); a[4 + j] = f2b(v1[j]); }
      af[mi] = a;
    }
#pragma unroll
    for (int cn = 0; cn < 8; ++cn) {
      u16x8 bf = *(const u16x8*)(Wt_in + (cn * 16 + lo) * 256 + kb);
      acc[0][cn] = MF(af[0], bf, acc[0][cn]);
      acc[1][cn] = MF(af[1], bf, acc[1][cn]);
    }
  }

  float binr[8];
#pragma unroll
  for (int cn = 0; cn < 8; ++cn) binr[cn] = b_in[cn * 16 + lo];

#pragma unroll
  for (int mi = 0; mi < 2; ++mi)
#pragma unroll
    for (int r = 0; r < 4; ++r) {
      const int s = w * 32 + mi * 16 + hi * 4 + r;
      if (s < 120) {
        const int sw = (s & 7) << 4;
#pragma unroll
        for (int cn = 0; cn < 8; ++cn) {
          const int cb = (cn * 16 + lo) * 2;
          *(unsigned short*)(GT + s * 256 + (cb ^ sw)) = f2b(acc[mi][cn][r] + binr[cn]);
        }
      }
    }
  {                                           // zero rows 120..144
    u16x8 zz = {0, 0, 0, 0, 0, 0, 0, 0};
    for (int idx = t; idx < 25 * 16; idx += 256) {
      int row = 120 + (idx >> 4), ch = (idx & 15) << 4;
      *(u16x8*)(GT + row * 256 + (ch ^ ((row & 7) << 4))) = zz;
    }
  }
  __syncthreads();

  // vectorized grid0 -> global (LDS re-read un-swizzles)
  unsigned short* gbp = gridb + (size_t)b * 144 * 128;
  for (int idx = t; idx < 144 * 16; idx += 256) {
    int row = idx >> 4, ch = (idx & 15) << 4;
    u16x8 v = *(const u16x8*)(GT + row * 256 + (ch ^ ((row & 7) << 4)));
    *(u16x8*)(gbp + row * 128 + ((idx & 15) << 3)) = v;
  }

  conv_body(GT, Wc0, convb0, 1, ybuf + (size_t)b * 144 * 128, partials, b, w, hi, lo);
}

// ---------------------------------------------------------------- k_conv2
// grid1 = grid0 + relu(bn1(y1)) staged (vectorized) + written back; conv dil=2.
__global__ __launch_bounds__(256) void k_conv2(
    unsigned short* __restrict__ gridb, unsigned short* __restrict__ ybuf,
    const float* __restrict__ statsP, const unsigned short* __restrict__ WcL,
    const float* __restrict__ convbL, float* __restrict__ partials) {
  __shared__ unsigned short Gt[145 * 128];
  char* GT = (char*)Gt;
  const int b = blockIdx.x, t = threadIdx.x;
  unsigned short* gbp = gridb + (size_t)b * 144 * 128;
  unsigned short* ybp = ybuf + (size_t)b * 144 * 128;
  const int c0 = (t & 15) * 8, prow = t >> 4;
  const f32x4 a0 = *(const f32x4*)(statsP + c0);
  const f32x4 a1 = *(const f32x4*)(statsP + c0 + 4);
  const f32x4 g0 = *(const f32x4*)(statsP + 128 + c0);
  const f32x4 g1 = *(const f32x4*)(statsP + 128 + c0 + 4);

#pragma unroll
  for (int it = 0; it < 9; ++it) {
    const int p = prow + 16 * it;             // covers 0..143
    u16x8 g = *(const u16x8*)(gbp + p * 128 + c0);
    u16x8 y = *(const u16x8*)(ybp + p * 128 + c0);
    u16x8 o;
#pragma unroll
    for (int j = 0; j < 4; ++j) {
      o[j]     = f2b(b2f(g[j])     + fmaxf(0.f, b2f(y[j])     * a0[j] + g0[j]));
      o[4 + j] = f2b(b2f(g[4 + j]) + fmaxf(0.f, b2f(y[4 + j]) * a1[j] + g1[j]));
    }
    *(u16x8*)(gbp + p * 128 + c0) = o;        // write back grid1 for k_out
    *(u16x8*)(GT + p * 256 + ((c0 * 2) ^ ((p & 7) << 4))) = o;
  }
  if (t < 16) {                               // row 144 = zeros (144&7==0: no swz)
    u16x8 zz = {0, 0, 0, 0, 0, 0, 0, 0};
    *(u16x8*)(GT + 144 * 256 + t * 16) = zz;
  }
  __syncthreads();

  conv_body(GT, WcL, convbL, 2, ybp, partials, b, t >> 6, (t & 63) >> 4, t & 15);
}

// ---------------------------------------------------------------- k_stats
__global__ void k_stats(const float* __restrict__ partials, const float* __restrict__ bn_g,
                        const float* __restrict__ bn_b, float* __restrict__ statsL, float invN) {
  const int c = blockIdx.x, t = threadIdx.x;
  float s1 = 0.f, s2 = 0.f;
  const float* p1 = partials + (size_t)c * 4096;
  const float* p2 = partials + (size_t)(128 + c) * 4096;
  for (int j = t; j < 4096; j += 256) { s1 += p1[j]; s2 += p2[j]; }
#pragma unroll
  for (int m = 1; m < 64; m <<= 1) { s1 += __shfl_xor(s1, m); s2 += __shfl_xor(s2, m); }
  __shared__ float r1[4], r2[4];
  if ((t & 63) == 0) { r1[t >> 6] = s1; r2[t >> 6] = s2; }
  __syncthreads();
  if (t == 0) {
    float S1 = r1[0] + r1[1] + r1[2] + r1[3];
    float S2 = r2[0] + r2[1] + r2[2] + r2[3];
    float mean = S1 * invN;
    float var = fmaxf(S2 * invN - mean * mean, 0.f);
    float a = bn_g[c] * rsqrtf(var + 1e-5f);
    statsL[c] = a;
    statsL[128 + c] = bn_b[c] - mean * a;
  }
}

// ---------------------------------------------------------------- k_out
// Gs[s][c] = grid1 + relu(bn2(y2)) (vectorized staging); h2 = Gs @ W_out;
// z = x + h2 + b_out; LayerNorm over h.
__global__ __launch_bounds__(256) void k_out(
    const unsigned short* __restrict__ gridb, const unsigned short* __restrict__ ybuf,
    const float* __restrict__ statsP, const unsigned short* __restrict__ Wt_out,
    const float* __restrict__ b_out, const float* __restrict__ x,
    const float* __restrict__ ln_g, const float* __restrict__ ln_b,
    float* __restrict__ out) {
  __shared__ unsigned short Gs[128 * 128];   // [s][c] bf16, 256B rows, swizzled
  char* GT = (char*)Gs;
  const int b = blockIdx.x, t = threadIdx.x;
  const unsigned short* gbp = gridb + (size_t)b * 144 * 128;
  const unsigned short* ybp = ybuf + (size_t)b * 144 * 128;
  const int c0 = (t & 15) * 8, prow = t >> 4;
  const f32x4 a0 = *(const f32x4*)(statsP + c0);
  const f32x4 a1 = *(const f32x4*)(statsP + c0 + 4);
  const f32x4 g0 = *(const f32x4*)(statsP + 128 + c0);
  const f32x4 g1 = *(const f32x4*)(statsP + 128 + c0 + 4);

#pragma unroll
  for (int it = 0; it < 8; ++it) {
    const int p = prow + 16 * it;             // 0..127
    u16x8 o = {0, 0, 0, 0, 0, 0, 0, 0};
    if (p < 120) {
      u16x8 g = *(const u16x8*)(gbp + p * 128 + c0);
      u16x8 y = *(const u16x8*)(ybp + p * 128 + c0);
#pragma unroll
      for (int j = 0; j < 4; ++j) {
        o[j]     = f2b(b2f(g[j])     + fmaxf(0.f, b2f(y[j])     * a0[j] + g0[j]));
        o[4 + j] = f2b(b2f(g[4 + j]) + fmaxf(0.f, b2f(y[4 + j]) * a1[j] + g1[j]));
      }
    }
    *(u16x8*)(GT + p * 256 + ((c0 * 2) ^ ((p & 7) << 4))) = o;
  }
  __syncthreads();

  const int l = t & 63, hi = l >> 4, lo = l & 15, w = t >> 6;
  const f32x4 Z = {0.f, 0.f, 0.f, 0.f};
  f32x4 acc[2][16];
#pragma unroll
  for (int mi = 0; mi < 2; ++mi)
#pragma unroll
    for (int nt = 0; nt < 16; ++nt) acc[mi][nt] = Z;

#pragma unroll
  for (int ks = 0; ks < 4; ++ks) {
    const int kb = ks * 32 + hi * 8;
    const int r0 = w * 32 + lo, r1 = r0 + 16;
    u16x8 A0 = *(const u16x8*)(GT + r0 * 256 + ((kb * 2) ^ ((r0 & 7) << 4)));
    u16x8 A1 = *(const u16x8*)(GT + r1 * 256 + ((kb * 2) ^ ((r1 & 7) << 4)));
#pragma unroll
    for (int nt = 0; nt < 16; ++nt) {
      u16x8 bf = *(const u16x8*)(Wt_out + (nt * 16 + lo) * 128 + kb);
      acc[0][nt] = MF(A0, bf, acc[0][nt]);
      acc[1][nt] = MF(A1, bf, acc[1][nt]);
    }
  }

  const float* xb = x + (size_t)b * 120 * 256;
  float* ob = out + (size_t)b * 120 * 256;
#pragma unroll
  for (int mi = 0; mi < 2; ++mi)
#pragma unroll
    for (int r = 0; r < 4; ++r) {
      const int row = w * 32 + mi * 16 + hi * 4 + r;
      if (row < 120) {   // uniform per 16-lane group -> shfl safe
        float z[16];
        float s1 = 0.f, s2 = 0.f;
#pragma unroll
        for (int nt = 0; nt < 16; ++nt) {
          const int col = nt * 16 + lo;
          float v = acc[mi][nt][r] + b_out[col] + xb[row * 256 + col];
          z[nt] = v; s1 += v; s2 += v * v;
        }
#pragma unroll
        for (int m = 1; m < 16; m <<= 1) { s1 += __shfl_xor(s1, m); s2 += __shfl_xor(s2, m); }
        const float mu = s1 * (1.f / 256.f);
        const float var = fmaxf(s2 * (1.f / 256.f) - mu * mu, 0.f);
        const float rs = rsqrtf(var + 1e-5f);
#pragma unroll
        for (int nt = 0; nt < 16; ++nt) {
          const int col = nt * 16 + lo;
          ob[row * 256 + col] = (z[nt] - mu) * rs * ln_g[col] + ln_b[col];
        }
      }
    }
}

// ---------------------------------------------------------------- launch
extern "C" void kernel_launch(void* const* d_in, const int* in_sizes, int n_in,
                              void* d_out, int out_size, void* d_ws, size_t ws_size,
                              hipStream_t stream) {
  (void)in_sizes; (void)n_in; (void)out_size; (void)ws_size;
  const float* x      = (const float*)d_in[0];
  const float* W_in   = (const float*)d_in[1];
  const float* b_in   = (const float*)d_in[2];
  const float* conv_w = (const float*)d_in[3];
  const float* conv_b = (const float*)d_in[4];
  const float* bn_g   = (const float*)d_in[5];
  const float* bn_b   = (const float*)d_in[6];
  const float* W_out  = (const float*)d_in[7];
  const float* b_out  = (const float*)d_in[8];
  const float* ln_g   = (const float*)d_in[9];
  const float* ln_b   = (const float*)d_in[10];

  char* ws = (char*)d_ws;
  size_t off = 0;
  auto alloc = [&](size_t bytes) { char* p = ws + off; off = (off + bytes + 255) & ~(size_t)255; return p; };
  unsigned short* Wt_in  = (unsigned short*)alloc(128 * 256 * 2);
  unsigned short* Wc     = (unsigned short*)alloc(2 * 9 * 128 * 128 * 2);
  unsigned short* Wt_out = (unsigned short*)alloc(256 * 128 * 2);
  float* stats           = (float*)alloc(2 * 256 * 4);
  float* partials        = (float*)alloc((size_t)256 * 4096 * 4);
  unsigned short* gridb  = (unsigned short*)alloc((size_t)4096 * 144 * 128 * 2);
  unsigned short* ybuf   = (unsigned short*)alloc((size_t)4096 * 144 * 128 * 2);

  const float invN = 1.f / (4096.f * 144.f);

  k_prep<<<256, 256, 0, stream>>>(W_in, conv_w, W_out, Wt_in, Wc, Wt_out);
  k_in<<<4096, 256, 0, stream>>>(x, Wt_in, b_in, Wc, conv_b, gridb, ybuf, partials);
  k_stats<<<128, 256, 0, stream>>>(partials, bn_g, bn_b, stats, invN);
  k_conv2<<<4096, 256, 0, stream>>>(gridb, ybuf, stats, Wc + 9 * 128 * 128, conv_b + 128, partials);
  k_stats<<<128, 256, 0, stream>>>(partials, bn_g + 128, bn_b + 128, stats + 256, invN);
  k_out<<<4096, 256, 0, stream>>>(gridb, ybuf, stats + 256, Wt_out, b_out, x, ln_g, ln_b, (float*)d_out);
}